// Round 1
// baseline (240.335 us; speedup 1.0000x reference)
//
#include <hip/hip_runtime.h>

// PolicyEncoder: out[n,:] = bias + w_state0[obs0[n]] + w_state1[obs1[n]]
//                          + w_act0[act0[n]] + w_act1[act1[n]]
// N = 262144 rows, D = 128 fp32.
// Memory-bound gather+sum. 32 lanes/row, one float4 per lane (512 B/row),
// 8 rows per 256-thread block.

#define PE_N 262144
#define PE_D 128
#define ROWS_PER_BLOCK 8

__global__ __launch_bounds__(256) void PolicyEncoder_79044578116211_kernel(
    const int* __restrict__ obs0, const int* __restrict__ obs1,
    const int* __restrict__ act0, const int* __restrict__ act1,
    const float* __restrict__ w_state0, const float* __restrict__ w_state1,
    const float* __restrict__ w_act0, const float* __restrict__ w_act1,
    const float* __restrict__ bias, float* __restrict__ out)
{
    const int t    = threadIdx.x;
    const int row  = blockIdx.x * ROWS_PER_BLOCK + (t >> 5);
    const int lane = t & 31;                 // float4 index within the row

    // Per-row indices (32 lanes read the same address -> L1 broadcast).
    const int i0 = obs0[row];
    const int i1 = obs1[row];
    const int a0 = act0[row];
    const int a1 = act1[row];

    const float4* s0 = (const float4*)(w_state0 + (size_t)i0 * PE_D);
    const float4* s1 = (const float4*)(w_state1 + (size_t)i1 * PE_D);
    const float4* v0 = (const float4*)(w_act0   + (size_t)a0 * PE_D);
    const float4* v1 = (const float4*)(w_act1   + (size_t)a1 * PE_D);
    const float4* b4 = (const float4*)bias;

    // Issue all loads up front; compiler schedules independent vmem ops.
    float4 xb = b4[lane];
    float4 x0 = s0[lane];
    float4 x1 = s1[lane];
    float4 y0 = v0[lane];
    float4 y1 = v1[lane];

    float4 acc;
    acc.x = xb.x + x0.x + x1.x + y0.x + y1.x;
    acc.y = xb.y + x0.y + x1.y + y0.y + y1.y;
    acc.z = xb.z + x0.z + x1.z + y0.z + y1.z;
    acc.w = xb.w + x0.w + x1.w + y0.w + y1.w;

    ((float4*)(out + (size_t)row * PE_D))[lane] = acc;
}

extern "C" void kernel_launch(void* const* d_in, const int* in_sizes, int n_in,
                              void* d_out, int out_size, void* d_ws, size_t ws_size,
                              hipStream_t stream) {
    const int*   obs0     = (const int*)  d_in[0];
    const int*   obs1     = (const int*)  d_in[1];
    const int*   act0     = (const int*)  d_in[2];
    const int*   act1     = (const int*)  d_in[3];
    const float* w_state0 = (const float*)d_in[4];
    const float* w_state1 = (const float*)d_in[5];
    const float* w_act0   = (const float*)d_in[6];
    const float* w_act1   = (const float*)d_in[7];
    const float* bias     = (const float*)d_in[8];
    float*       out      = (float*)d_out;

    const int grid = PE_N / ROWS_PER_BLOCK;  // 32768 blocks
    PolicyEncoder_79044578116211_kernel<<<grid, 256, 0, stream>>>(
        obs0, obs1, act0, act1, w_state0, w_state1, w_act0, w_act1, bias, out);
}

// Round 3
// 236.352 us; speedup vs baseline: 1.0168x; 1.0168x over previous
//
#include <hip/hip_runtime.h>

// PolicyEncoder: out[n,:] = bias + w_state0[obs0[n]] + w_state1[obs1[n]]
//                          + w_act0[act0[n]] + w_act1[act1[n]]
// N = 262144 rows, D = 128 fp32. Memory-bound gather+sum.
// R2: 2 rows per thread (more outstanding gathers per wave) +
//     non-temporal stores via native ext_vector_type (HIP float4 rejected
//     by __builtin_nontemporal_store).

#define PE_N 262144
#define PE_D 128
#define ROWS_PER_BLOCK 16   // 8 row-slots * 2 rows per thread

typedef float v4f __attribute__((ext_vector_type(4)));

__global__ __launch_bounds__(256) void PolicyEncoder_79044578116211_kernel(
    const int* __restrict__ obs0, const int* __restrict__ obs1,
    const int* __restrict__ act0, const int* __restrict__ act1,
    const float* __restrict__ w_state0, const float* __restrict__ w_state1,
    const float* __restrict__ w_act0, const float* __restrict__ w_act1,
    const float* __restrict__ bias, float* __restrict__ out)
{
    const int t    = threadIdx.x;
    const int slot = t >> 5;          // 0..7
    const int lane = t & 31;          // float4 index within a row

    const int rowA = blockIdx.x * ROWS_PER_BLOCK + slot;
    const int rowB = rowA + 8;

    // Row indices for both rows (lanes in a row read the same addr -> broadcast).
    const int iA0 = obs0[rowA], iB0 = obs0[rowB];
    const int iA1 = obs1[rowA], iB1 = obs1[rowB];
    const int aA0 = act0[rowA], aB0 = act0[rowB];
    const int aA1 = act1[rowA], aB1 = act1[rowB];

    const v4f* b4 = (const v4f*)bias;
    v4f xb = b4[lane];

    // 8 independent gathers in flight.
    v4f A0 = ((const v4f*)(w_state0 + (size_t)iA0 * PE_D))[lane];
    v4f A1 = ((const v4f*)(w_state1 + (size_t)iA1 * PE_D))[lane];
    v4f A2 = ((const v4f*)(w_act0   + (size_t)aA0 * PE_D))[lane];
    v4f A3 = ((const v4f*)(w_act1   + (size_t)aA1 * PE_D))[lane];
    v4f B0 = ((const v4f*)(w_state0 + (size_t)iB0 * PE_D))[lane];
    v4f B1 = ((const v4f*)(w_state1 + (size_t)iB1 * PE_D))[lane];
    v4f B2 = ((const v4f*)(w_act0   + (size_t)aB0 * PE_D))[lane];
    v4f B3 = ((const v4f*)(w_act1   + (size_t)aB1 * PE_D))[lane];

    v4f accA = xb + A0 + A1 + A2 + A3;
    v4f accB = xb + B0 + B1 + B2 + B3;

    // Streaming writes: non-temporal so they don't evict table rows from L2.
    v4f* outA = (v4f*)(out + (size_t)rowA * PE_D) + lane;
    v4f* outB = (v4f*)(out + (size_t)rowB * PE_D) + lane;
    __builtin_nontemporal_store(accA, outA);
    __builtin_nontemporal_store(accB, outB);
}

extern "C" void kernel_launch(void* const* d_in, const int* in_sizes, int n_in,
                              void* d_out, int out_size, void* d_ws, size_t ws_size,
                              hipStream_t stream) {
    const int*   obs0     = (const int*)  d_in[0];
    const int*   obs1     = (const int*)  d_in[1];
    const int*   act0     = (const int*)  d_in[2];
    const int*   act1     = (const int*)  d_in[3];
    const float* w_state0 = (const float*)d_in[4];
    const float* w_state1 = (const float*)d_in[5];
    const float* w_act0   = (const float*)d_in[6];
    const float* w_act1   = (const float*)d_in[7];
    const float* bias     = (const float*)d_in[8];
    float*       out      = (float*)d_out;

    const int grid = PE_N / ROWS_PER_BLOCK;  // 16384 blocks
    PolicyEncoder_79044578116211_kernel<<<grid, 256, 0, stream>>>(
        obs0, obs1, act0, act1, w_state0, w_state1, w_act0, w_act1, bias, out);
}